// Round 1
// baseline (2865.881 us; speedup 1.0000x reference)
//
#include <hip/hip_runtime.h>

#define HH   6
#define NN   343
#define BB   512
#define DIMC 192
#define MM   (BB*NN)      // 175616
#define NT   352          // padded N (22 tiles of 16)

#define KS_PAD 40         // K LDS row stride (ushort units)
#define VT_PAD 360        // V^T LDS row stride
#define P_PAD  360        // P LDS row stride

// workspace offsets (bytes, 256-aligned)
#define OFF_TABLE 0                       // [2197][8] f32
#define OFF_RPB   70400                   // [6][343][343] f32
#define OFF_QB    2894080                 // [M][192] bf16
#define OFF_KB    (OFF_QB + 67436544)
#define OFF_VB    (OFF_KB + 67436544)
#define OFF_CROSS (OFF_VB + 67436544)
#define OFF_SQ    (OFF_CROSS + 67436544)  // [B*H*N] f32
#define OFF_SK    (OFF_SQ + 4214784)
// total = 281,069,824 bytes

typedef __bf16 bf16x8 __attribute__((ext_vector_type(8)));
typedef float  f32x4  __attribute__((ext_vector_type(4)));

__device__ __forceinline__ f32x4 mfma16(bf16x8 a, bf16x8 b, f32x4 c) {
    return __builtin_amdgcn_mfma_f32_16x16x32_bf16(a, b, c, 0, 0, 0);
}

// ---------------- K1: CPB MLP -> table[2197][8] ----------------
__global__ __launch_bounds__(256) void cpb_table_kernel(
    const float* __restrict__ rel_table, const float* __restrict__ w1,
    const float* __restrict__ b1, const float* __restrict__ w2,
    float* __restrict__ table)
{
    int i = blockIdx.x;
    int t = threadIdx.x;
    float t0 = rel_table[i*3+0], t1 = rel_table[i*3+1], t2 = rel_table[i*3+2];
    float acc[HH];
    #pragma unroll
    for (int h = 0; h < HH; h++) acc[h] = 0.f;
    for (int j = t; j < 512; j += 256) {
        float hv = w1[j*3+0]*t0 + w1[j*3+1]*t1 + w1[j*3+2]*t2 + b1[j];
        hv = fmaxf(hv, 0.f);
        #pragma unroll
        for (int h = 0; h < HH; h++) acc[h] += w2[h*512+j] * hv;
    }
    __shared__ float red[256*HH];
    #pragma unroll
    for (int h = 0; h < HH; h++) red[t*HH+h] = acc[h];
    __syncthreads();
    for (int s = 128; s > 0; s >>= 1) {
        if (t < s) {
            #pragma unroll
            for (int h = 0; h < HH; h++) red[t*HH+h] += red[(t+s)*HH+h];
        }
        __syncthreads();
    }
    if (t < HH) table[(size_t)i*8 + t] = red[t];
}

// ---------------- K2: gather + 16*sigmoid -> rpb[6][343][343] ----------------
__global__ __launch_bounds__(256) void rpb_kernel(
    const float* __restrict__ table, const int* __restrict__ rp_index,
    float* __restrict__ rpb)
{
    int id = blockIdx.x*256 + threadIdx.x;
    if (id >= HH*NN*NN) return;
    int h  = id / (NN*NN);
    int nm = id - h*(NN*NN);
    float v = table[(size_t)rp_index[nm]*8 + h];
    rpb[id] = 16.f / (1.f + __expf(-v));
}

// ---------------- GEMM: f32 in -> bf16 out, tile 64x192, K=192, up to 2 phases ----------------
__global__ __launch_bounds__(256) void gemm_f32in(
    const float* __restrict__ A,
    const float* __restrict__ W0, const float* __restrict__ bias0, __bf16* __restrict__ D0,
    const float* __restrict__ W1, const float* __restrict__ bias1, __bf16* __restrict__ D1)
{
    __shared__ __bf16 As[64][200];
    __shared__ __bf16 Ws[192][40];
    int m0 = blockIdx.x * 64;
    int t  = threadIdx.x;
    // stage A (64x192 f32 -> bf16)
    #pragma unroll
    for (int i = 0; i < 12; i++) {
        int f = t + 256*i;            // float4 index
        int row = f / 48, ch = (f - row*48) * 4;
        float4 v = *(const float4*)(A + (size_t)(m0+row)*DIMC + ch);
        __bf16* dst = &As[row][ch];
        dst[0] = (__bf16)v.x; dst[1] = (__bf16)v.y; dst[2] = (__bf16)v.z; dst[3] = (__bf16)v.w;
    }
    int wave = t >> 6, lane = t & 63, lr = lane & 15, lg = lane >> 4;
    for (int phase = 0; phase < 2; phase++) {
        const float* W    = phase ? W1 : W0;
        if (!W) break;
        const float* bias = phase ? bias1 : bias0;
        __bf16*      D    = phase ? D1 : D0;
        f32x4 acc[12];
        #pragma unroll
        for (int i = 0; i < 12; i++) acc[i] = (f32x4){0.f,0.f,0.f,0.f};
        for (int ks = 0; ks < 6; ks++) {
            __syncthreads();
            #pragma unroll
            for (int i = 0; i < 6; i++) {
                int f = t + 256*i;    // float4 index into [192][32]
                int row = f / 8, ch = (f - row*8) * 4;
                float4 v = *(const float4*)(W + (size_t)row*DIMC + ks*32 + ch);
                __bf16* dst = &Ws[row][ch];
                dst[0] = (__bf16)v.x; dst[1] = (__bf16)v.y; dst[2] = (__bf16)v.z; dst[3] = (__bf16)v.w;
            }
            __syncthreads();
            bf16x8 afrag = *(const bf16x8*)&As[16*wave + lr][ks*32 + 8*lg];
            #pragma unroll
            for (int ct = 0; ct < 12; ct++) {
                bf16x8 bfrag = *(const bf16x8*)&Ws[16*ct + lr][8*lg];
                acc[ct] = mfma16(afrag, bfrag, acc[ct]);
            }
        }
        #pragma unroll
        for (int ct = 0; ct < 12; ct++) {
            int c = 16*ct + lr;
            float bv = bias ? bias[c] : 0.f;
            #pragma unroll
            for (int reg = 0; reg < 4; reg++) {
                int r = m0 + 16*wave + 4*lg + reg;
                D[(size_t)r*DIMC + c] = (__bf16)(acc[ct][reg] + bv);
            }
        }
    }
}

// ---------------- proj GEMM: bf16 in -> f32 out + bias ----------------
__global__ __launch_bounds__(256) void gemm_proj(
    const __bf16* __restrict__ A, const float* __restrict__ W,
    const float* __restrict__ bias, float* __restrict__ D)
{
    __shared__ __bf16 As[64][200];
    __shared__ __bf16 Ws[192][40];
    int m0 = blockIdx.x * 64;
    int t  = threadIdx.x;
    #pragma unroll
    for (int i = 0; i < 6; i++) {
        int f = t + 256*i;            // ushort8 index
        int row = f / 24, ch = (f - row*24) * 8;
        uint4 v = *(const uint4*)(A + (size_t)(m0+row)*DIMC + ch);
        *(uint4*)&As[row][ch] = v;
    }
    int wave = t >> 6, lane = t & 63, lr = lane & 15, lg = lane >> 4;
    f32x4 acc[12];
    #pragma unroll
    for (int i = 0; i < 12; i++) acc[i] = (f32x4){0.f,0.f,0.f,0.f};
    for (int ks = 0; ks < 6; ks++) {
        __syncthreads();
        #pragma unroll
        for (int i = 0; i < 6; i++) {
            int f = t + 256*i;
            int row = f / 8, ch = (f - row*8) * 4;
            float4 v = *(const float4*)(W + (size_t)row*DIMC + ks*32 + ch);
            __bf16* dst = &Ws[row][ch];
            dst[0] = (__bf16)v.x; dst[1] = (__bf16)v.y; dst[2] = (__bf16)v.z; dst[3] = (__bf16)v.w;
        }
        __syncthreads();
        bf16x8 afrag = *(const bf16x8*)&As[16*wave + lr][ks*32 + 8*lg];
        #pragma unroll
        for (int ct = 0; ct < 12; ct++) {
            bf16x8 bfrag = *(const bf16x8*)&Ws[16*ct + lr][8*lg];
            acc[ct] = mfma16(afrag, bfrag, acc[ct]);
        }
    }
    #pragma unroll
    for (int ct = 0; ct < 12; ct++) {
        int c = 16*ct + lr;
        float bv = bias[c];
        #pragma unroll
        for (int reg = 0; reg < 4; reg++) {
            int r = m0 + 16*wave + 4*lg + reg;
            D[(size_t)r*DIMC + c] = acc[ct][reg] + bv;
        }
    }
}

// ---------------- norms: sq = scale/|q|, sk = 1/|k| ----------------
__global__ __launch_bounds__(256) void norms_kernel(
    const __bf16* __restrict__ q, const __bf16* __restrict__ k,
    const float* __restrict__ ls, float* __restrict__ sq, float* __restrict__ sk)
{
    int id = blockIdx.x*256 + threadIdx.x;      // exactly B*H*N threads
    int b   = id / (HH*NN);
    int rem = id - b*(HH*NN);
    int h   = rem / NN;
    int n   = rem - h*NN;
    size_t base = ((size_t)(b*NN + n))*DIMC + 32*h;
    const uint4* qp = (const uint4*)(q + base);
    const uint4* kp = (const uint4*)(k + base);
    float s0 = 0.f, s1 = 0.f;
    #pragma unroll
    for (int i = 0; i < 4; i++) {
        union { uint4 u; __bf16 e[8]; } a, c;
        a.u = qp[i]; c.u = kp[i];
        #pragma unroll
        for (int j = 0; j < 8; j++) {
            float v = (float)a.e[j]; s0 += v*v;
            float w = (float)c.e[j]; s1 += w*w;
        }
    }
    float scale = __expf(fminf(ls[h], 4.6051702f));
    sq[id] = scale / fmaxf(sqrtf(s0), 1e-12f);
    sk[id] = 1.f  / fmaxf(sqrtf(s1), 1e-12f);
}

// ---------------- fused attention: one block per (b,h) ----------------
__global__ __launch_bounds__(256) void attn_kernel(
    const __bf16* __restrict__ qb, const __bf16* __restrict__ kb, const __bf16* __restrict__ vb,
    const float* __restrict__ sq, const float* __restrict__ sk,
    const float* __restrict__ rpb, const float* __restrict__ mask,
    __bf16* __restrict__ cross)
{
    extern __shared__ char smem[];
    __bf16* Ks  = (__bf16*)smem;             // [352][40]
    __bf16* VTs = (__bf16*)(smem + 28160);   // [32][360]
    float*  rnk = (float*) (smem + 51200);   // [352]
    __bf16* Ps  = (__bf16*)(smem + 52608);   // [4][16][360]

    int bh = blockIdx.x;
    int b  = bh / HH;
    int h  = bh - b*HH;
    int w  = b & 63;
    int t  = threadIdx.x;

    // stage K (row-major) and V (transposed), zero-pad rows 343..351
    #pragma unroll
    for (int i = 0; i < 6; i++) {
        int c = t + 256*i;
        if (c >= NT*4) break;
        int m = c >> 2, part = c & 3;
        if (m < NN) {
            size_t gbase = ((size_t)(b*NN + m))*DIMC + 32*h + part*8;
            uint4 kv = *(const uint4*)(kb + gbase);
            *(uint4*)&Ks[m*KS_PAD + part*8] = kv;
            union { uint4 u; __bf16 e[8]; } vv;
            vv.u = *(const uint4*)(vb + gbase);
            #pragma unroll
            for (int j = 0; j < 8; j++) VTs[(part*8+j)*VT_PAD + m] = vv.e[j];
        } else {
            *(uint4*)&Ks[m*KS_PAD + part*8] = make_uint4(0,0,0,0);
            #pragma unroll
            for (int j = 0; j < 8; j++) VTs[(part*8+j)*VT_PAD + m] = (__bf16)0.f;
        }
    }
    for (int m = t; m < NT; m += 256) rnk[m] = (m < NN) ? sk[(size_t)bh*NN + m] : 0.f;
    __syncthreads();

    int wave = t >> 6, lane = t & 63, lr = lane & 15, lg = lane >> 4;
    __bf16* Pw = Ps + wave*16*P_PAD;
    const float* rpb_h  = rpb  + (size_t)h*NN*NN;
    const float* mask_w = mask + (size_t)w*NN*NN;

    for (int qt = wave; qt < 22; qt += 4) {
        // Q fragment straight from global (A: row=lr, k=8*lg+j)
        int rag = min(16*qt + lr, NN-1);
        bf16x8 qfrag = *(const bf16x8*)(qb + ((size_t)(b*NN + rag))*DIMC + 32*h + 8*lg);
        float sqr[4];
        const float* rpb_r[4];
        const float* mask_r[4];
        #pragma unroll
        for (int reg = 0; reg < 4; reg++) {
            int rc = min(16*qt + 4*lg + reg, NN-1);
            sqr[reg]    = sq[(size_t)bh*NN + rc];
            rpb_r[reg]  = rpb_h  + (size_t)rc*NN;
            mask_r[reg] = mask_w + (size_t)rc*NN;
        }
        // QK^T
        f32x4 s[22];
        #pragma unroll
        for (int mt = 0; mt < 22; mt++) {
            bf16x8 kfrag = *(const bf16x8*)&Ks[(16*mt + lr)*KS_PAD + 8*lg];
            s[mt] = mfma16(qfrag, kfrag, (f32x4){0.f,0.f,0.f,0.f});
        }
        // bias + exp + P to LDS + denom partial
        float dsum[4] = {0.f,0.f,0.f,0.f};
        #pragma unroll
        for (int mt = 0; mt < 22; mt++) {
            int m  = 16*mt + lr;
            int mc = min(m, NN-1);
            float rk = rnk[m];
            #pragma unroll
            for (int reg = 0; reg < 4; reg++) {
                float sv = s[mt][reg] * sqr[reg] * rk + rpb_r[reg][mc] + mask_r[reg][mc];
                if (m >= NN) sv = -1e30f;
                float p = __expf(sv - 26.f);
                dsum[reg] += p;
                Pw[(4*lg + reg)*P_PAD + m] = (__bf16)p;
            }
        }
        #pragma unroll
        for (int reg = 0; reg < 4; reg++) {
            float v = dsum[reg];
            v += __shfl_xor(v, 1); v += __shfl_xor(v, 2);
            v += __shfl_xor(v, 4); v += __shfl_xor(v, 8);
            dsum[reg] = 1.f / v;
        }
        // PV
        f32x4 acc0 = {0.f,0.f,0.f,0.f}, acc1 = {0.f,0.f,0.f,0.f};
        #pragma unroll
        for (int ks = 0; ks < 11; ks++) {
            bf16x8 pf = *(const bf16x8*)&Pw[lr*P_PAD + 32*ks + 8*lg];
            bf16x8 v0 = *(const bf16x8*)&VTs[lr*VT_PAD + 32*ks + 8*lg];
            bf16x8 v1 = *(const bf16x8*)&VTs[(16+lr)*VT_PAD + 32*ks + 8*lg];
            acc0 = mfma16(pf, v0, acc0);
            acc1 = mfma16(pf, v1, acc1);
        }
        #pragma unroll
        for (int reg = 0; reg < 4; reg++) {
            int r = 16*qt + 4*lg + reg;
            if (r < NN) {
                size_t base = ((size_t)(b*NN + r))*DIMC + 32*h;
                cross[base + lr]      = (__bf16)(acc0[reg] * dsum[reg]);
                cross[base + 16 + lr] = (__bf16)(acc1[reg] * dsum[reg]);
            }
        }
    }
}

extern "C" void kernel_launch(void* const* d_in, const int* in_sizes, int n_in,
                              void* d_out, int out_size, void* d_ws, size_t ws_size,
                              hipStream_t stream) {
    const float* x           = (const float*)d_in[0];
    const float* y           = (const float*)d_in[1];
    const float* mask        = (const float*)d_in[2];
    const float* qkv1_w      = (const float*)d_in[3];
    const float* qkv2_w      = (const float*)d_in[4];
    const float* v1_bias     = (const float*)d_in[6];
    const float* q2_bias     = (const float*)d_in[7];
    const float* logit_scale = (const float*)d_in[9];
    const float* cpb_w1      = (const float*)d_in[10];
    const float* cpb_b1      = (const float*)d_in[11];
    const float* cpb_w2      = (const float*)d_in[12];
    const float* proj_w      = (const float*)d_in[13];
    const float* proj_b      = (const float*)d_in[14];
    const float* rel_table   = (const float*)d_in[15];
    const int*   rp_index    = (const int*)d_in[16];

    char* ws = (char*)d_ws;
    float*  table   = (float*)(ws + OFF_TABLE);
    float*  rpb     = (float*)(ws + OFF_RPB);
    __bf16* q_bf    = (__bf16*)(ws + OFF_QB);
    __bf16* k_bf    = (__bf16*)(ws + OFF_KB);
    __bf16* v_bf    = (__bf16*)(ws + OFF_VB);
    __bf16* crossb  = (__bf16*)(ws + OFF_CROSS);
    float*  sq      = (float*)(ws + OFF_SQ);
    float*  sk      = (float*)(ws + OFF_SK);

    cpb_table_kernel<<<2197, 256, 0, stream>>>(rel_table, cpb_w1, cpb_b1, cpb_w2, table);
    rpb_kernel<<<(HH*NN*NN + 255)/256, 256, 0, stream>>>(table, rp_index, rpb);
    // x -> k (no bias), v (+v1_bias)
    gemm_f32in<<<MM/64, 256, 0, stream>>>(x, qkv1_w + 192*192, nullptr, k_bf,
                                          qkv1_w + 384*192, v1_bias, v_bf);
    // y -> q (+q2_bias)
    gemm_f32in<<<MM/64, 256, 0, stream>>>(y, qkv2_w, q2_bias, q_bf,
                                          nullptr, nullptr, nullptr);
    norms_kernel<<<(BB*HH*NN)/256, 256, 0, stream>>>(q_bf, k_bf, logit_scale, sq, sk);

    hipFuncSetAttribute((const void*)attn_kernel,
                        hipFuncAttributeMaxDynamicSharedMemorySize, 98688);
    attn_kernel<<<BB*HH, 256, 98688, stream>>>(q_bf, k_bf, v_bf, sq, sk, rpb, mask, crossb);

    gemm_proj<<<MM/64, 256, 0, stream>>>(crossb, proj_w, proj_b, (float*)d_out);
}

// Round 2
// 861.447 us; speedup vs baseline: 3.3268x; 3.3268x over previous
//
#include <hip/hip_runtime.h>

#define HH   6
#define NN   343
#define BB   512
#define DIMC 192
#define MM   (BB*NN)      // 175616

// workspace offsets (bytes)
#define OFF_TABLE 0                        // [2197][8] f32
#define OFF_R     70400                    // [6][343][352] f32  (exp(rpb-26), zero tail)
#define OFF_MB    2968064                  // [64*343][16] u32   (bit-packed mask, lane-repacked)
#define OFF_QB    4372992                  // [M][192] bf16 (normalized*scale)
#define OFF_KB    (OFF_QB + 67436544)      // [M][192] bf16 (normalized)
#define OFF_VB    (OFF_KB + 67436544)
#define OFF_CROSS (OFF_VB + 67436544)
// end = 274,119,168 bytes

typedef __bf16 bf16x8 __attribute__((ext_vector_type(8)));
typedef float  f32x4  __attribute__((ext_vector_type(4)));

__device__ __forceinline__ f32x4 mfma16(bf16x8 a, bf16x8 b, f32x4 c) {
    return __builtin_amdgcn_mfma_f32_16x16x32_bf16(a, b, c, 0, 0, 0);
}

__device__ __forceinline__ unsigned pack2(float a, float b) {
    union { __bf16 h[2]; unsigned u; } x;
    x.h[0] = (__bf16)a; x.h[1] = (__bf16)b;
    return x.u;
}

// ---------------- K1: CPB MLP -> table[2197][8] ----------------
__global__ __launch_bounds__(256) void cpb_table_kernel(
    const float* __restrict__ rel_table, const float* __restrict__ w1,
    const float* __restrict__ b1, const float* __restrict__ w2,
    float* __restrict__ table)
{
    int i = blockIdx.x;
    int t = threadIdx.x;
    float t0 = rel_table[i*3+0], t1 = rel_table[i*3+1], t2 = rel_table[i*3+2];
    float acc[HH];
    #pragma unroll
    for (int h = 0; h < HH; h++) acc[h] = 0.f;
    for (int j = t; j < 512; j += 256) {
        float hv = w1[j*3+0]*t0 + w1[j*3+1]*t1 + w1[j*3+2]*t2 + b1[j];
        hv = fmaxf(hv, 0.f);
        #pragma unroll
        for (int h = 0; h < HH; h++) acc[h] += w2[h*512+j] * hv;
    }
    __shared__ float red[256*HH];
    #pragma unroll
    for (int h = 0; h < HH; h++) red[t*HH+h] = acc[h];
    __syncthreads();
    for (int s = 128; s > 0; s >>= 1) {
        if (t < s) {
            #pragma unroll
            for (int h = 0; h < HH; h++) red[t*HH+h] += red[(t+s)*HH+h];
        }
        __syncthreads();
    }
    if (t < HH) table[(size_t)i*8 + t] = red[t];
}

// ---------------- K2: R = exp(16*sigmoid(gather) - 26), [6][343][352] ----------------
__global__ __launch_bounds__(256) void r_kernel(
    const float* __restrict__ table, const int* __restrict__ rp_index,
    float* __restrict__ R)
{
    int id = blockIdx.x*256 + threadIdx.x;
    if (id >= HH*NN*352) return;
    int h   = id / (NN*352);
    int rem = id - h*(NN*352);
    int n   = rem / 352;
    int mc  = rem - n*352;
    float out = 0.f;
    if (mc < NN) {
        float v = table[(size_t)rp_index[n*NN+mc]*8 + h];
        float r = 16.f / (1.f + __expf(-v));
        out = __expf(r - 26.f);
    }
    R[id] = out;
}

// ---------------- K3: bit-pack mask, lane-stream layout ----------------
// layout: mb[w*343+n][16 words]; words 4*lg+t (t=0..2) hold bits b where
// tile mt=8t+(b>>2), reg r=b&3, m=16*mt+4*lg+r; bit = (mask > -50)
__global__ __launch_bounds__(256) void mbits_kernel(
    const float* __restrict__ mask, unsigned* __restrict__ mb)
{
    int id  = blockIdx.x*256 + threadIdx.x;   // 64*343*4 threads
    int lg  = id & 3;
    int row = id >> 2;                         // w*343 + n
    const float* mrow = mask + (size_t)row*NN;
    unsigned out[3];
    #pragma unroll
    for (int t = 0; t < 3; t++) {
        unsigned u = 0;
        #pragma unroll
        for (int bb = 0; bb < 32; bb++) {
            int mt = 8*t + (bb>>2), r = bb & 3;
            int m  = 16*mt + 4*lg + r;
            if (m < NN && mrow[m] > -50.f) u |= (1u << bb);
        }
        out[t] = u;
    }
    *(uint4*)(mb + (size_t)row*16 + 4*lg) = make_uint4(out[0], out[1], out[2], 0u);
}

// ---------------- GEMM: f32 in -> bf16 out, tile 64x192, K=192, up to 2 phases ----------------
__global__ __launch_bounds__(256) void gemm_f32in(
    const float* __restrict__ A,
    const float* __restrict__ W0, const float* __restrict__ bias0, __bf16* __restrict__ D0,
    const float* __restrict__ W1, const float* __restrict__ bias1, __bf16* __restrict__ D1)
{
    __shared__ __bf16 As[64][200];
    __shared__ __bf16 Ws[192][40];
    int m0 = blockIdx.x * 64;
    int t  = threadIdx.x;
    #pragma unroll
    for (int i = 0; i < 12; i++) {
        int f = t + 256*i;
        int row = f / 48, ch = (f - row*48) * 4;
        float4 v = *(const float4*)(A + (size_t)(m0+row)*DIMC + ch);
        __bf16* dst = &As[row][ch];
        dst[0] = (__bf16)v.x; dst[1] = (__bf16)v.y; dst[2] = (__bf16)v.z; dst[3] = (__bf16)v.w;
    }
    int wave = t >> 6, lane = t & 63, lr = lane & 15, lg = lane >> 4;
    for (int phase = 0; phase < 2; phase++) {
        const float* W    = phase ? W1 : W0;
        if (!W) break;
        const float* bias = phase ? bias1 : bias0;
        __bf16*      D    = phase ? D1 : D0;
        f32x4 acc[12];
        #pragma unroll
        for (int i = 0; i < 12; i++) acc[i] = (f32x4){0.f,0.f,0.f,0.f};
        for (int ks = 0; ks < 6; ks++) {
            __syncthreads();
            #pragma unroll
            for (int i = 0; i < 6; i++) {
                int f = t + 256*i;
                int row = f / 8, ch = (f - row*8) * 4;
                float4 v = *(const float4*)(W + (size_t)row*DIMC + ks*32 + ch);
                __bf16* dst = &Ws[row][ch];
                dst[0] = (__bf16)v.x; dst[1] = (__bf16)v.y; dst[2] = (__bf16)v.z; dst[3] = (__bf16)v.w;
            }
            __syncthreads();
            bf16x8 afrag = *(const bf16x8*)&As[16*wave + lr][ks*32 + 8*lg];
            #pragma unroll
            for (int ct = 0; ct < 12; ct++) {
                bf16x8 bfrag = *(const bf16x8*)&Ws[16*ct + lr][8*lg];
                acc[ct] = mfma16(afrag, bfrag, acc[ct]);
            }
        }
        #pragma unroll
        for (int ct = 0; ct < 12; ct++) {
            int c = 16*ct + lr;
            float bv = bias ? bias[c] : 0.f;
            #pragma unroll
            for (int reg = 0; reg < 4; reg++) {
                int r = m0 + 16*wave + 4*lg + reg;
                D[(size_t)r*DIMC + c] = (__bf16)(acc[ct][reg] + bv);
            }
        }
    }
}

// ---------------- proj GEMM: bf16 in -> f32 out + bias ----------------
__global__ __launch_bounds__(256) void gemm_proj(
    const __bf16* __restrict__ A, const float* __restrict__ W,
    const float* __restrict__ bias, float* __restrict__ D)
{
    __shared__ __bf16 As[64][200];
    __shared__ __bf16 Ws[192][40];
    int m0 = blockIdx.x * 64;
    int t  = threadIdx.x;
    #pragma unroll
    for (int i = 0; i < 6; i++) {
        int f = t + 256*i;
        int row = f / 24, ch = (f - row*24) * 8;
        uint4 v = *(const uint4*)(A + (size_t)(m0+row)*DIMC + ch);
        *(uint4*)&As[row][ch] = v;
    }
    int wave = t >> 6, lane = t & 63, lr = lane & 15, lg = lane >> 4;
    f32x4 acc[12];
    #pragma unroll
    for (int i = 0; i < 12; i++) acc[i] = (f32x4){0.f,0.f,0.f,0.f};
    for (int ks = 0; ks < 6; ks++) {
        __syncthreads();
        #pragma unroll
        for (int i = 0; i < 6; i++) {
            int f = t + 256*i;
            int row = f / 8, ch = (f - row*8) * 4;
            float4 v = *(const float4*)(W + (size_t)row*DIMC + ks*32 + ch);
            __bf16* dst = &Ws[row][ch];
            dst[0] = (__bf16)v.x; dst[1] = (__bf16)v.y; dst[2] = (__bf16)v.z; dst[3] = (__bf16)v.w;
        }
        __syncthreads();
        bf16x8 afrag = *(const bf16x8*)&As[16*wave + lr][ks*32 + 8*lg];
        #pragma unroll
        for (int ct = 0; ct < 12; ct++) {
            bf16x8 bfrag = *(const bf16x8*)&Ws[16*ct + lr][8*lg];
            acc[ct] = mfma16(afrag, bfrag, acc[ct]);
        }
    }
    #pragma unroll
    for (int ct = 0; ct < 12; ct++) {
        int c = 16*ct + lr;
        float bv = bias[c];
        #pragma unroll
        for (int reg = 0; reg < 4; reg++) {
            int r = m0 + 16*wave + 4*lg + reg;
            D[(size_t)r*DIMC + c] = acc[ct][reg] + bv;
        }
    }
}

// ---------------- normalize q,k in place: q *= scale/|q|, k *= 1/|k| ----------------
__global__ __launch_bounds__(256) void normalize_kernel(
    __bf16* __restrict__ q, __bf16* __restrict__ k, const float* __restrict__ ls)
{
    int id = blockIdx.x*256 + threadIdx.x;      // B*H*N threads
    int b   = id / (HH*NN);
    int rem = id - b*(HH*NN);
    int h   = rem / NN;
    int n   = rem - h*NN;
    size_t base = ((size_t)(b*NN + n))*DIMC + 32*h;
    union U { uint4 u[4]; __bf16 e[32]; };
    U qu, ku;
    #pragma unroll
    for (int i = 0; i < 4; i++) {
        qu.u[i] = ((const uint4*)(q + base))[i];
        ku.u[i] = ((const uint4*)(k + base))[i];
    }
    float s0 = 0.f, s1 = 0.f;
    #pragma unroll
    for (int j = 0; j < 32; j++) {
        float a = (float)qu.e[j]; s0 += a*a;
        float c = (float)ku.e[j]; s1 += c*c;
    }
    float scale = __expf(fminf(ls[h], 4.6051702f));
    float fq = scale / fmaxf(sqrtf(s0), 1e-12f);
    float fk = 1.f   / fmaxf(sqrtf(s1), 1e-12f);
    #pragma unroll
    for (int j = 0; j < 32; j++) {
        qu.e[j] = (__bf16)((float)qu.e[j] * fq);
        ku.e[j] = (__bf16)((float)ku.e[j] * fk);
    }
    #pragma unroll
    for (int i = 0; i < 4; i++) {
        ((uint4*)(q + base))[i] = qu.u[i];
        ((uint4*)(k + base))[i] = ku.u[i];
    }
}

// ---------------- fused attention: one block (4 waves) per (b,h) ----------------
// swapped QK^T: s = mfma(K,Q) -> lane holds q = q0+lr (fixed), m = 16*mt+4*lg+reg
__global__ __launch_bounds__(256, 4) void attn_kernel(
    const __bf16* __restrict__ qb, const __bf16* __restrict__ kb, const __bf16* __restrict__ vb,
    const float* __restrict__ R, const unsigned* __restrict__ mbits,
    __bf16* __restrict__ cross)
{
    __shared__ __bf16 VTs[32*368];       // V^T [d=32][m pitch 368], m<352 valid
    __shared__ __bf16 Pws[4*16*104];     // per-wave P chunk, dual slot (48-ushort slots)

    int bh = blockIdx.x;
    int b  = bh / HH;
    int h  = bh - b*HH;
    int w  = b & 63;
    int t  = threadIdx.x;

    const __bf16* Kb = kb + ((size_t)b*NN)*DIMC + 32*h;
    const __bf16* Vb = vb + ((size_t)b*NN)*DIMC + 32*h;
    const __bf16* Qb = qb + ((size_t)b*NN)*DIMC + 32*h;

    // stage V^T
    for (int idx = t; idx < NN*4; idx += 256) {
        int m = idx >> 2, part = idx & 3;
        union { uint4 u; __bf16 e[8]; } vv;
        vv.u = *(const uint4*)(Vb + (size_t)m*DIMC + 8*part);
        #pragma unroll
        for (int j = 0; j < 8; j++) VTs[(8*part+j)*368 + m] = vv.e[j];
    }
    // zero-pad m = 343..351
    for (int idx = t; idx < 9*32; idx += 256) {
        int m = NN + (idx % 9), d = idx / 9;
        VTs[d*368 + m] = (__bf16)0.f;
    }
    __syncthreads();

    int wave = t >> 6, lane = t & 63, lr = lane & 15, lg = lane >> 4;
    __bf16* Pw = Pws + wave*16*104;
    const f32x4 zero = {0.f,0.f,0.f,0.f};

    for (int qt = wave; qt < 22; qt += 4) {
        int q0 = 16*qt;
        int rc = min(q0 + lr, NN-1);
        bf16x8 qf = *(const bf16x8*)(Qb + (size_t)rc*DIMC + 8*lg);
        const float* Rrow = R + ((size_t)h*NN + rc)*352 + 4*lg;
        uint4 mw = *(const uint4*)(mbits + ((size_t)(w*NN + rc))*16 + 4*lg);
        unsigned b0 = mw.x, b1 = mw.y, b2 = mw.z;

        float dsum = 0.f;
        f32x4 acc0 = zero, acc1 = zero;

        #pragma unroll 2
        for (int ks = 0; ks < 11; ks++) {
            int ma = 32*ks + lr;
            int mb_ = 32*ks + 16 + lr;
            bf16x8 kfa = *(const bf16x8*)(Kb + (size_t)min(ma, NN-1)*DIMC + 8*lg);
            bf16x8 kfb = *(const bf16x8*)(Kb + (size_t)min(mb_, NN-1)*DIMC + 8*lg);
            f32x4 ra = *(const f32x4*)(Rrow + 32*ks);
            f32x4 rb = *(const f32x4*)(Rrow + 32*ks + 16);

            f32x4 s0 = mfma16(kfa, qf, zero);
            f32x4 s1 = mfma16(kfb, qf, zero);

            unsigned nib = b0 & 0xFFu;
            b0 = (b0 >> 8) | (b1 << 24);
            b1 = (b1 >> 8) | (b2 << 24);
            b2 >>= 8;

            float pv[8];
            #pragma unroll
            for (int r = 0; r < 4; r++) {
                float pa = ((nib >> r) & 1)     ? __expf(s0[r]) * ra[r] : 0.f;
                float pb = ((nib >> (4+r)) & 1) ? __expf(s1[r]) * rb[r] : 0.f;
                dsum += pa + pb;
                pv[r] = pa; pv[4+r] = pb;
            }

            int slot  = (ks & 1) * 48;
            int pbase = lr*104 + slot + 4*lg;
            *(unsigned*)&Pw[pbase]      = pack2(pv[0], pv[1]);
            *(unsigned*)&Pw[pbase + 2]  = pack2(pv[2], pv[3]);
            *(unsigned*)&Pw[pbase + 16] = pack2(pv[4], pv[5]);
            *(unsigned*)&Pw[pbase + 18] = pack2(pv[6], pv[7]);

            bf16x8 paf = *(const bf16x8*)&Pw[lr*104 + slot + 8*lg];
            bf16x8 v0  = *(const bf16x8*)&VTs[lr*368 + 32*ks + 8*lg];
            bf16x8 v1  = *(const bf16x8*)&VTs[(16+lr)*368 + 32*ks + 8*lg];
            acc0 = mfma16(paf, v0, acc0);
            acc1 = mfma16(paf, v1, acc1);
        }

        dsum += __shfl_xor(dsum, 16);
        dsum += __shfl_xor(dsum, 32);
        float dinv = 1.f / dsum;

        #pragma unroll
        for (int reg = 0; reg < 4; reg++) {
            float dv = __shfl(dinv, 4*lg + reg);
            int q = q0 + 4*lg + reg;
            if (q < NN) {
                size_t cb = ((size_t)b*NN + q)*DIMC + 32*h;
                cross[cb + lr]      = (__bf16)(acc0[reg] * dv);
                cross[cb + 16 + lr] = (__bf16)(acc1[reg] * dv);
            }
        }
    }
}

extern "C" void kernel_launch(void* const* d_in, const int* in_sizes, int n_in,
                              void* d_out, int out_size, void* d_ws, size_t ws_size,
                              hipStream_t stream) {
    const float* x           = (const float*)d_in[0];
    const float* y           = (const float*)d_in[1];
    const float* mask        = (const float*)d_in[2];
    const float* qkv1_w      = (const float*)d_in[3];
    const float* qkv2_w      = (const float*)d_in[4];
    const float* v1_bias     = (const float*)d_in[6];
    const float* q2_bias     = (const float*)d_in[7];
    const float* logit_scale = (const float*)d_in[9];
    const float* cpb_w1      = (const float*)d_in[10];
    const float* cpb_b1      = (const float*)d_in[11];
    const float* cpb_w2      = (const float*)d_in[12];
    const float* proj_w      = (const float*)d_in[13];
    const float* proj_b      = (const float*)d_in[14];
    const float* rel_table   = (const float*)d_in[15];
    const int*   rp_index    = (const int*)d_in[16];

    char* ws = (char*)d_ws;
    float*    table  = (float*)(ws + OFF_TABLE);
    float*    R      = (float*)(ws + OFF_R);
    unsigned* mb     = (unsigned*)(ws + OFF_MB);
    __bf16*   q_bf   = (__bf16*)(ws + OFF_QB);
    __bf16*   k_bf   = (__bf16*)(ws + OFF_KB);
    __bf16*   v_bf   = (__bf16*)(ws + OFF_VB);
    __bf16*   crossb = (__bf16*)(ws + OFF_CROSS);

    cpb_table_kernel<<<2197, 256, 0, stream>>>(rel_table, cpb_w1, cpb_b1, cpb_w2, table);
    r_kernel<<<(HH*NN*352 + 255)/256, 256, 0, stream>>>(table, rp_index, R);
    mbits_kernel<<<(64*NN*4)/256, 256, 0, stream>>>(mask, mb);
    // x -> k (no bias), v (+v1_bias)
    gemm_f32in<<<MM/64, 256, 0, stream>>>(x, qkv1_w + 192*192, nullptr, k_bf,
                                          qkv1_w + 384*192, v1_bias, v_bf);
    // y -> q (+q2_bias)
    gemm_f32in<<<MM/64, 256, 0, stream>>>(y, qkv2_w, q2_bias, q_bf,
                                          nullptr, nullptr, nullptr);
    normalize_kernel<<<(BB*HH*NN)/256, 256, 0, stream>>>(q_bf, k_bf, logit_scale);

    attn_kernel<<<BB*HH, 256, 0, stream>>>(q_bf, k_bf, v_bf, R, mb, crossb);

    gemm_proj<<<MM/64, 256, 0, stream>>>(crossb, proj_w, proj_b, (float*)d_out);
}

// Round 4
// 672.497 us; speedup vs baseline: 4.2616x; 1.2810x over previous
//
#include <hip/hip_runtime.h>

#define HH   6
#define NN   343
#define BB   512
#define DIMC 192
#define MM   (BB*NN)      // 175616

// workspace offsets (bytes)
#define OFF_TABLE 0                        // [2197][8] f32
#define OFF_R     70400                    // [6][343][352] f32  (exp(rpb-26), zero tail)
#define OFF_MB    2968064                  // [64*343][16] u32   (bit-packed mask, lane-repacked)
#define OFF_QB    4372992                  // [M][192] bf16 (normalized * scale * log2e)
#define OFF_KB    (OFF_QB + 67436544)      // [M][192] bf16 (normalized)
#define OFF_VB    (OFF_KB + 67436544)
#define OFF_CROSS (OFF_VB + 67436544)
// end = 274,119,168 bytes

typedef __bf16 bf16x8 __attribute__((ext_vector_type(8)));
typedef float  f32x4  __attribute__((ext_vector_type(4)));

__device__ __forceinline__ f32x4 mfma16(bf16x8 a, bf16x8 b, f32x4 c) {
    return __builtin_amdgcn_mfma_f32_16x16x32_bf16(a, b, c, 0, 0, 0);
}

__device__ __forceinline__ unsigned pack2(float a, float b) {
    union { __bf16 h[2]; unsigned u; } x;
    x.h[0] = (__bf16)a; x.h[1] = (__bf16)b;
    return x.u;
}

// ---------------- K1: CPB MLP -> table[2197][8] ----------------
__global__ __launch_bounds__(256) void cpb_table_kernel(
    const float* __restrict__ rel_table, const float* __restrict__ w1,
    const float* __restrict__ b1, const float* __restrict__ w2,
    float* __restrict__ table)
{
    int i = blockIdx.x;
    int t = threadIdx.x;
    float t0 = rel_table[i*3+0], t1 = rel_table[i*3+1], t2 = rel_table[i*3+2];
    float acc[HH];
    #pragma unroll
    for (int h = 0; h < HH; h++) acc[h] = 0.f;
    for (int j = t; j < 512; j += 256) {
        float hv = w1[j*3+0]*t0 + w1[j*3+1]*t1 + w1[j*3+2]*t2 + b1[j];
        hv = fmaxf(hv, 0.f);
        #pragma unroll
        for (int h = 0; h < HH; h++) acc[h] += w2[h*512+j] * hv;
    }
    __shared__ float red[256*HH];
    #pragma unroll
    for (int h = 0; h < HH; h++) red[t*HH+h] = acc[h];
    __syncthreads();
    for (int s = 128; s > 0; s >>= 1) {
        if (t < s) {
            #pragma unroll
            for (int h = 0; h < HH; h++) red[t*HH+h] += red[(t+s)*HH+h];
        }
        __syncthreads();
    }
    if (t < HH) table[(size_t)i*8 + t] = red[t];
}

// ---------------- K2: R = exp(16*sigmoid(gather) - 26), [6][343][352] ----------------
__global__ __launch_bounds__(256) void r_kernel(
    const float* __restrict__ table, const int* __restrict__ rp_index,
    float* __restrict__ R)
{
    int id = blockIdx.x*256 + threadIdx.x;
    if (id >= HH*NN*352) return;
    int h   = id / (NN*352);
    int rem = id - h*(NN*352);
    int n   = rem / 352;
    int mc  = rem - n*352;
    float out = 0.f;
    if (mc < NN) {
        float v = table[(size_t)rp_index[n*NN+mc]*8 + h];
        float r = 16.f / (1.f + __expf(-v));
        out = __expf(r - 26.f);
    }
    R[id] = out;
}

// ---------------- K3: bit-pack mask, lane-stream layout ----------------
__global__ __launch_bounds__(256) void mbits_kernel(
    const float* __restrict__ mask, unsigned* __restrict__ mb)
{
    int id  = blockIdx.x*256 + threadIdx.x;   // 64*343*4 threads
    int lg  = id & 3;
    int row = id >> 2;                         // w*343 + n
    const float* mrow = mask + (size_t)row*NN;
    unsigned out[3];
    #pragma unroll
    for (int t = 0; t < 3; t++) {
        unsigned u = 0;
        #pragma unroll
        for (int bb = 0; bb < 32; bb++) {
            int mt = 8*t + (bb>>2), r = bb & 3;
            int m  = 16*mt + 4*lg + r;
            if (m < NN && mrow[m] > -50.f) u |= (1u << bb);
        }
        out[t] = u;
    }
    *(uint4*)(mb + (size_t)row*16 + 4*lg) = make_uint4(out[0], out[1], out[2], 0u);
}

// ---------------- GEMM: f32 in -> bf16 out, tile 64x192, K=192, up to 2 phases ----------------
// norm: 0 = none, 1 = k-norm (1/|k|), 2 = q-norm (scale*log2e/|q|)
__global__ __launch_bounds__(256) void gemm_f32in(
    const float* __restrict__ A, const float* __restrict__ ls,
    const float* __restrict__ W0, const float* __restrict__ bias0, int norm0, __bf16* __restrict__ D0,
    const float* __restrict__ W1, const float* __restrict__ bias1, int norm1, __bf16* __restrict__ D1)
{
    __shared__ __bf16 As[64][200];
    __shared__ __bf16 Ws[192][40];
    int m0 = blockIdx.x * 64;
    int t  = threadIdx.x;
    #pragma unroll
    for (int i = 0; i < 12; i++) {
        int f = t + 256*i;
        int row = f / 48, ch = (f - row*48) * 4;
        float4 v = *(const float4*)(A + (size_t)(m0+row)*DIMC + ch);
        __bf16* dst = &As[row][ch];
        dst[0] = (__bf16)v.x; dst[1] = (__bf16)v.y; dst[2] = (__bf16)v.z; dst[3] = (__bf16)v.w;
    }
    int wave = t >> 6, lane = t & 63, lr = lane & 15, lg = lane >> 4;
    for (int phase = 0; phase < 2; phase++) {
        const float* W    = phase ? W1 : W0;
        if (!W) break;
        const float* bias = phase ? bias1 : bias0;
        int          nrm  = phase ? norm1 : norm0;
        __bf16*      D    = phase ? D1 : D0;
        f32x4 acc[12];
        #pragma unroll
        for (int i = 0; i < 12; i++) acc[i] = (f32x4){0.f,0.f,0.f,0.f};
        for (int ks = 0; ks < 6; ks++) {
            __syncthreads();
            #pragma unroll
            for (int i = 0; i < 6; i++) {
                int f = t + 256*i;
                int row = f / 8, ch = (f - row*8) * 4;
                float4 v = *(const float4*)(W + (size_t)row*DIMC + ks*32 + ch);
                __bf16* dst = &Ws[row][ch];
                dst[0] = (__bf16)v.x; dst[1] = (__bf16)v.y; dst[2] = (__bf16)v.z; dst[3] = (__bf16)v.w;
            }
            __syncthreads();
            bf16x8 afrag = *(const bf16x8*)&As[16*wave + lr][ks*32 + 8*lg];
            #pragma unroll
            for (int ct = 0; ct < 12; ct++) {
                bf16x8 bfrag = *(const bf16x8*)&Ws[16*ct + lr][8*lg];
                acc[ct] = mfma16(afrag, bfrag, acc[ct]);
            }
        }
        // bias
        if (bias) {
            #pragma unroll
            for (int ct = 0; ct < 12; ct++) {
                float bv = bias[16*ct + lr];
                #pragma unroll
                for (int reg = 0; reg < 4; reg++) acc[ct][reg] += bv;
            }
        }
        // fused per-head cosine normalization (rows = 4*lg+reg, head h = cols 32h..32h+31)
        if (nrm) {
            #pragma unroll
            for (int h = 0; h < HH; h++) {
                float sc = 1.f;
                if (nrm == 2) sc = __expf(fminf(ls[h], 4.6051702f)) * 1.4426950408889634f;
                #pragma unroll
                for (int reg = 0; reg < 4; reg++) {
                    float ss = acc[2*h][reg]*acc[2*h][reg] + acc[2*h+1][reg]*acc[2*h+1][reg];
                    ss += __shfl_xor(ss, 1); ss += __shfl_xor(ss, 2);
                    ss += __shfl_xor(ss, 4); ss += __shfl_xor(ss, 8);
                    float f = sc / fmaxf(sqrtf(ss), 1e-12f);
                    acc[2*h][reg]   *= f;
                    acc[2*h+1][reg] *= f;
                }
            }
        }
        #pragma unroll
        for (int ct = 0; ct < 12; ct++) {
            int c = 16*ct + lr;
            #pragma unroll
            for (int reg = 0; reg < 4; reg++) {
                int r = m0 + 16*wave + 4*lg + reg;
                D[(size_t)r*DIMC + c] = (__bf16)acc[ct][reg];
            }
        }
    }
}

// ---------------- proj GEMM: bf16 in -> f32 out + bias ----------------
__global__ __launch_bounds__(256) void gemm_proj(
    const __bf16* __restrict__ A, const float* __restrict__ W,
    const float* __restrict__ bias, float* __restrict__ D)
{
    __shared__ __bf16 As[64][200];
    __shared__ __bf16 Ws[192][40];
    int m0 = blockIdx.x * 64;
    int t  = threadIdx.x;
    #pragma unroll
    for (int i = 0; i < 6; i++) {
        int f = t + 256*i;
        int row = f / 24, ch = (f - row*24) * 8;
        uint4 v = *(const uint4*)(A + (size_t)(m0+row)*DIMC + ch);
        *(uint4*)&As[row][ch] = v;
    }
    int wave = t >> 6, lane = t & 63, lr = lane & 15, lg = lane >> 4;
    f32x4 acc[12];
    #pragma unroll
    for (int i = 0; i < 12; i++) acc[i] = (f32x4){0.f,0.f,0.f,0.f};
    for (int ks = 0; ks < 6; ks++) {
        __syncthreads();
        #pragma unroll
        for (int i = 0; i < 6; i++) {
            int f = t + 256*i;
            int row = f / 8, ch = (f - row*8) * 4;
            float4 v = *(const float4*)(W + (size_t)row*DIMC + ks*32 + ch);
            __bf16* dst = &Ws[row][ch];
            dst[0] = (__bf16)v.x; dst[1] = (__bf16)v.y; dst[2] = (__bf16)v.z; dst[3] = (__bf16)v.w;
        }
        __syncthreads();
        bf16x8 afrag = *(const bf16x8*)&As[16*wave + lr][ks*32 + 8*lg];
        #pragma unroll
        for (int ct = 0; ct < 12; ct++) {
            bf16x8 bfrag = *(const bf16x8*)&Ws[16*ct + lr][8*lg];
            acc[ct] = mfma16(afrag, bfrag, acc[ct]);
        }
    }
    #pragma unroll
    for (int ct = 0; ct < 12; ct++) {
        int c = 16*ct + lr;
        float bv = bias[c];
        #pragma unroll
        for (int reg = 0; reg < 4; reg++) {
            int r = m0 + 16*wave + 4*lg + reg;
            D[(size_t)r*DIMC + c] = acc[ct][reg] + bv;
        }
    }
}

// ---------------- fused attention: one block (4 waves) per (b,h), 2 q-tiles/wave ----------------
// swapped QK^T: s = mfma(K,Q) -> lane holds q = q0+lr (fixed), m = 32ks+{0,16}+4lg+reg
// VTs pitch 392 ushorts (196 dwords == 4 mod 32): linear addressing, 2-way max conflict
#define VT_PITCH 392
__global__ __launch_bounds__(256, 4) void attn_kernel(
    const __bf16* __restrict__ qb, const __bf16* __restrict__ kb, const __bf16* __restrict__ vb,
    const float* __restrict__ R, const unsigned* __restrict__ mbits,
    __bf16* __restrict__ cross)
{
    __shared__ __bf16 VTs[32*VT_PITCH];  // V^T [d=32][m pitch 392], 25088 B
    __shared__ __bf16 Ps[4*32*40];       // per-wave P: rows 16*tile+lr, pitch 40, 10240 B

    int bh = blockIdx.x;
    int b  = bh / HH;
    int h  = bh - b*HH;
    int w  = b & 63;
    int t  = threadIdx.x;

    const __bf16* Kb = kb + ((size_t)b*NN)*DIMC + 32*h;
    const __bf16* Vb = vb + ((size_t)b*NN)*DIMC + 32*h;
    const __bf16* Qb = qb + ((size_t)b*NN)*DIMC + 32*h;

    // stage V^T (consecutive threads -> consecutive m)
    for (int idx = t; idx < NN*4; idx += 256) {
        int part = idx / NN;
        int m    = idx - part*NN;
        union { uint4 u; __bf16 e[8]; } vv;
        vv.u = *(const uint4*)(Vb + (size_t)m*DIMC + 8*part);
        #pragma unroll
        for (int j = 0; j < 8; j++) {
            int d = 8*part + j;
            VTs[d*VT_PITCH + m] = vv.e[j];
        }
    }
    for (int idx = t; idx < 32*9; idx += 256) {
        int d = idx / 9, m = NN + (idx - d*9);
        VTs[d*VT_PITCH + m] = (__bf16)0.f;
    }
    __syncthreads();

    int wave = t >> 6, lane = t & 63, lr = lane & 15, lg = lane >> 4;
    __bf16* Pw = Ps + wave*32*40;
    const f32x4 zero = {0.f,0.f,0.f,0.f};

    int p = wave;
    for (int s = 0; s < 3; s++, p += 4) {
        if (p >= 11) break;
        int q00 = 32*p, q01 = 32*p + 16;
        int rc0 = min(q00 + lr, NN-1);
        int rc1 = min(q01 + lr, NN-1);
        bf16x8 qf0 = *(const bf16x8*)(Qb + (size_t)rc0*DIMC + 8*lg);
        bf16x8 qf1 = *(const bf16x8*)(Qb + (size_t)rc1*DIMC + 8*lg);
        const float* Rrow0 = R + ((size_t)h*NN + rc0)*352 + 4*lg;
        const float* Rrow1 = R + ((size_t)h*NN + rc1)*352 + 4*lg;
        uint4 mu0 = *(const uint4*)(mbits + ((size_t)(w*NN + rc0))*16 + 4*lg);
        uint4 mu1 = *(const uint4*)(mbits + ((size_t)(w*NN + rc1))*16 + 4*lg);
        unsigned t0a = mu0.x, t0b = mu0.y, t0c = mu0.z;
        unsigned t1a = mu1.x, t1b = mu1.y, t1c = mu1.z;

        float dsum0 = 0.f, dsum1 = 0.f;
        f32x4 acc00 = zero, acc01 = zero, acc10 = zero, acc11 = zero;

        // prefetch ks = 0
        bf16x8 kfa = *(const bf16x8*)(Kb + (size_t)lr*DIMC + 8*lg);
        bf16x8 kfb = *(const bf16x8*)(Kb + (size_t)(16+lr)*DIMC + 8*lg);
        f32x4 ra0 = *(const f32x4*)(Rrow0);
        f32x4 rb0 = *(const f32x4*)(Rrow0 + 16);
        f32x4 ra1 = *(const f32x4*)(Rrow1);
        f32x4 rb1 = *(const f32x4*)(Rrow1 + 16);

        for (int ks = 0; ks < 11; ks++) {
            // prefetch ks+1
            bf16x8 kfa_n = kfa, kfb_n = kfb;
            f32x4 ra0_n = ra0, rb0_n = rb0, ra1_n = ra1, rb1_n = rb1;
            if (ks < 10) {
                int ma = 32*(ks+1) + lr;
                kfa_n = *(const bf16x8*)(Kb + (size_t)min(ma, NN-1)*DIMC + 8*lg);
                kfb_n = *(const bf16x8*)(Kb + (size_t)min(ma+16, NN-1)*DIMC + 8*lg);
                ra0_n = *(const f32x4*)(Rrow0 + 32*(ks+1));
                rb0_n = *(const f32x4*)(Rrow0 + 32*(ks+1) + 16);
                ra1_n = *(const f32x4*)(Rrow1 + 32*(ks+1));
                rb1_n = *(const f32x4*)(Rrow1 + 32*(ks+1) + 16);
            }

            f32x4 s0a = mfma16(kfa, qf0, zero);
            f32x4 s0b = mfma16(kfb, qf0, zero);
            f32x4 s1a = mfma16(kfa, qf1, zero);
            f32x4 s1b = mfma16(kfb, qf1, zero);

            unsigned nib0 = t0a & 0xFFu;
            t0a = (t0a >> 8) | (t0b << 24); t0b = (t0b >> 8) | (t0c << 24); t0c >>= 8;
            unsigned nib1 = t1a & 0xFFu;
            t1a = (t1a >> 8) | (t1b << 24); t1b = (t1b >> 8) | (t1c << 24); t1c >>= 8;

            // tile 0 softmax numerators
            {
                float pa[4], pb[4];
                #pragma unroll
                for (int r = 0; r < 4; r++) {
                    pa[r] = ((nib0 >> r) & 1)     ? exp2f(s0a[r]) * ra0[r] : 0.f;
                    pb[r] = ((nib0 >> (4+r)) & 1) ? exp2f(s0b[r]) * rb0[r] : 0.f;
                    dsum0 += pa[r] + pb[r];
                }
                unsigned* pw = (unsigned*)&Pw[lr*40 + 4*lg];
                pw[0] = pack2(pa[0], pa[1]); pw[1] = pack2(pa[2], pa[3]);
                pw[8] = pack2(pb[0], pb[1]); pw[9] = pack2(pb[2], pb[3]);
            }
            // tile 1
            {
                float pa[4], pb[4];
                #pragma unroll
                for (int r = 0; r < 4; r++) {
                    pa[r] = ((nib1 >> r) & 1)     ? exp2f(s1a[r]) * ra1[r] : 0.f;
                    pb[r] = ((nib1 >> (4+r)) & 1) ? exp2f(s1b[r]) * rb1[r] : 0.f;
                    dsum1 += pa[r] + pb[r];
                }
                unsigned* pw = (unsigned*)&Pw[(16+lr)*40 + 4*lg];
                pw[0] = pack2(pa[0], pa[1]); pw[1] = pack2(pa[2], pa[3]);
                pw[8] = pack2(pb[0], pb[1]); pw[9] = pack2(pb[2], pb[3]);
            }

            bf16x8 pa0 = *(const bf16x8*)&Pw[lr*40 + 8*lg];
            bf16x8 pa1 = *(const bf16x8*)&Pw[(16+lr)*40 + 8*lg];
            bf16x8 v0  = *(const bf16x8*)&VTs[lr*VT_PITCH      + 32*ks + 8*lg];
            bf16x8 v1  = *(const bf16x8*)&VTs[(16+lr)*VT_PITCH + 32*ks + 8*lg];
            acc00 = mfma16(pa0, v0, acc00);
            acc01 = mfma16(pa0, v1, acc01);
            acc10 = mfma16(pa1, v0, acc10);
            acc11 = mfma16(pa1, v1, acc11);

            kfa = kfa_n; kfb = kfb_n;
            ra0 = ra0_n; rb0 = rb0_n; ra1 = ra1_n; rb1 = rb1_n;
        }

        dsum0 += __shfl_xor(dsum0, 16); dsum0 += __shfl_xor(dsum0, 32);
        dsum1 += __shfl_xor(dsum1, 16); dsum1 += __shfl_xor(dsum1, 32);
        float dinv0 = 1.f / dsum0;
        float dinv1 = 1.f / dsum1;

        #pragma unroll
        for (int reg = 0; reg < 4; reg++) {
            float dv0 = __shfl(dinv0, 4*lg + reg);
            float dv1 = __shfl(dinv1, 4*lg + reg);
            int q0v = q00 + 4*lg + reg;
            int q1v = q01 + 4*lg + reg;
            if (q0v < NN) {
                size_t cb = ((size_t)b*NN + q0v)*DIMC + 32*h;
                cross[cb + lr]      = (__bf16)(acc00[reg] * dv0);
                cross[cb + 16 + lr] = (__bf16)(acc01[reg] * dv0);
            }
            if (q1v < NN) {
                size_t cb = ((size_t)b*NN + q1v)*DIMC + 32*h;
                cross[cb + lr]      = (__bf16)(acc10[reg] * dv1);
                cross[cb + 16 + lr] = (__bf16)(acc11[reg] * dv1);
            }
        }
    }
}

extern "C" void kernel_launch(void* const* d_in, const int* in_sizes, int n_in,
                              void* d_out, int out_size, void* d_ws, size_t ws_size,
                              hipStream_t stream) {
    const float* x           = (const float*)d_in[0];
    const float* y           = (const float*)d_in[1];
    const float* mask        = (const float*)d_in[2];
    const float* qkv1_w      = (const float*)d_in[3];
    const float* qkv2_w      = (const float*)d_in[4];
    const float* v1_bias     = (const float*)d_in[6];
    const float* q2_bias     = (const float*)d_in[7];
    const float* logit_scale = (const float*)d_in[9];
    const float* cpb_w1      = (const float*)d_in[10];
    const float* cpb_b1      = (const float*)d_in[11];
    const float* cpb_w2      = (const float*)d_in[12];
    const float* proj_w      = (const float*)d_in[13];
    const float* proj_b      = (const float*)d_in[14];
    const float* rel_table   = (const float*)d_in[15];
    const int*   rp_index    = (const int*)d_in[16];

    char* ws = (char*)d_ws;
    float*    table  = (float*)(ws + OFF_TABLE);
    float*    R      = (float*)(ws + OFF_R);
    unsigned* mb     = (unsigned*)(ws + OFF_MB);
    __bf16*   q_bf   = (__bf16*)(ws + OFF_QB);
    __bf16*   k_bf   = (__bf16*)(ws + OFF_KB);
    __bf16*   v_bf   = (__bf16*)(ws + OFF_VB);
    __bf16*   crossb = (__bf16*)(ws + OFF_CROSS);

    cpb_table_kernel<<<2197, 256, 0, stream>>>(rel_table, cpb_w1, cpb_b1, cpb_w2, table);
    r_kernel<<<(HH*NN*352 + 255)/256, 256, 0, stream>>>(table, rp_index, R);
    mbits_kernel<<<(64*NN*4)/256, 256, 0, stream>>>(mask, mb);
    // x -> k (norm, no bias), v (+v1_bias, no norm)
    gemm_f32in<<<MM/64, 256, 0, stream>>>(x, logit_scale,
                                          qkv1_w + 192*192, nullptr, 1, k_bf,
                                          qkv1_w + 384*192, v1_bias, 0, v_bf);
    // y -> q (+q2_bias, norm+scale*log2e)
    gemm_f32in<<<MM/64, 256, 0, stream>>>(y, logit_scale,
                                          qkv2_w, q2_bias, 2, q_bf,
                                          nullptr, nullptr, 0, nullptr);

    attn_kernel<<<BB*HH, 256, 0, stream>>>(q_bf, k_bf, v_bf, R, mb, crossb);

    gemm_proj<<<MM/64, 256, 0, stream>>>(crossb, proj_w, proj_b, (float*)d_out);
}